// Round 8
// baseline (84.603 us; speedup 1.0000x reference)
//
#include <hip/hip_runtime.h>
#include <hip/hip_bf16.h>

typedef float f32x2 __attribute__((ext_vector_type(2)));

#define IMG_H 384
#define IMG_W 384
#define KSZ 9
#define KR 4
#define TW 16                 // tile width (px) = 8 pixel-pairs
#define TH 8                  // tile height
#define NP (TW/2)             // 8 pairs per row
#define HW (TW + 2*KR)        // 24 halo width
#define HH (TH + 2*KR)        // 16 halo height
#define PST 36                // plane row stride (dwords); 36 % 32 == 4 -> conflict-free floor
#define PLANE (IMG_H * IMG_W)
#define REPS 8                // measurement round: 8 redundant passes (identical writes)

static __device__ __forceinline__ f32x2 mk2(float a, float b) { f32x2 r; r.x = a; r.y = b; return r; }

__global__ __launch_bounds__(192) void abf_kernel(
    const float* __restrict__ input,   // [2][3][384][384]
    const float* __restrict__ sigmas,  // [2][2][384][384]
    float* __restrict__ out)           // [2][3][384][384]
{
    __shared__ float s_in[3 * HH * PST];          // 6.75 KB, channel-planar
    __shared__ f32x2 s_comb[2][NP * TH][4];       // tz=1,2 partial sums, 4 KB

    const int b      = blockIdx.z & 1;   // batch; blockIdx.z>>1 = replica (redundant work)
    const int tile_x = blockIdx.x * TW;
    const int tile_y = blockIdx.y * TH;
    const int tx = threadIdx.x;  // 0..7  pair column
    const int ty = threadIdx.y;  // 0..7  row
    const int tz = threadIdx.z;  // 0..2  dy-group (wave-uniform)
    const int tid = (tz * TH + ty) * NP + tx;

    // ---- stage 24x16 halo, channel-planar, conflict-free stride ----
    const float* inb = input + (size_t)b * 3 * PLANE;
    for (int p = tid; p < 3 * HH * HW; p += 192) {
        int c   = p / (HH * HW);
        int rem = p - c * (HH * HW);
        int y   = rem / HW;
        int x   = rem - y * HW;
        int gy  = tile_y + y - KR;
        int gx  = tile_x + x - KR;
        float v = 0.f;
        if (gy >= 0 && gy < IMG_H && gx >= 0 && gx < IMG_W)
            v = inb[c * PLANE + gy * IMG_W + gx];
        s_in[(c * HH + y) * PST + x] = v;
    }
    __syncthreads();

    const int lx = 2 * tx;           // tile-local col of pixel A (pixel B = lx+1)
    const int ox = tile_x + lx;
    const int oy = tile_y + ty;

    const float* sgb = sigmas + (size_t)b * 2 * PLANE;
    const int sidx = oy * IMG_W + ox;
    const float sA0 = sgb[sidx],          sB0 = sgb[sidx + 1];
    const float sA1 = sgb[PLANE + sidx],  sB1 = sgb[PLANE + sidx + 1];
    const float isA = 1.f / (fabsf(sA0) + 1e-12f);
    const float isB = 1.f / (fabsf(sB0) + 1e-12f);
    const float irA = 1.f / (fabsf(sA1) + 1e-12f);
    const float irB = 1.f / (fabsf(sB1) + 1e-12f);
    // w = exp2(dsq*B + (rx2+ry2)*A), packed over the two pixels
    const f32x2 A = mk2(-0.72134752f * isA * isA, -0.72134752f * isB * isB);
    const f32x2 B = mk2(-0.72134752f * irA * irA, -0.72134752f * irB * irB);

    const int cb = (ty + KR) * PST + lx + KR;
    const f32x2 cen0 = mk2(s_in[0 * HH * PST + cb], s_in[0 * HH * PST + cb + 1]);
    const f32x2 cen1 = mk2(s_in[1 * HH * PST + cb], s_in[1 * HH * PST + cb + 1]);
    const f32x2 cen2 = mk2(s_in[2 * HH * PST + cb], s_in[2 * HH * PST + cb + 1]);

    f32x2 wsum = mk2(0.f, 0.f), a0 = wsum, a1 = wsum, a2 = wsum;

    // tz handles dy in {3tz, 3tz+1, 3tz+2} : perfect 3-way balance
    #pragma unroll 1
    for (int r = 0; r < 3; ++r) {
        const int dy = tz * 3 + r;
        const float ry2 = (float)((dy - KR) * (dy - KR));
        const f32x2 syA = ry2 * A;
        const int r0 = (0 * HH + ty + dy) * PST + lx;
        const int r1 = (1 * HH + ty + dy) * PST + lx;
        const int r2 = (2 * HH + ty + dy) * PST + lx;

        // register sliding window: 10 dwords per channel row, loaded once,
        // static indices only (adjacent pairs merge into ds_read2_b32)
        float w0[10], w1[10], w2[10];
        #pragma unroll
        for (int j = 0; j < 10; ++j) {
            w0[j] = s_in[r0 + j];
            w1[j] = s_in[r1 + j];
            w2[j] = s_in[r2 + j];
        }

        #pragma unroll
        for (int dx = 0; dx < KSZ; ++dx) {
            const float rx2 = (float)((dx - KR) * (dx - KR));
            const f32x2 v0 = mk2(w0[dx], w0[dx + 1]);
            const f32x2 v1 = mk2(w1[dx], w1[dx + 1]);
            const f32x2 v2 = mk2(w2[dx], w2[dx + 1]);
            const f32x2 d0 = v0 - cen0;
            const f32x2 d1 = v1 - cen1;
            const f32x2 d2 = v2 - cen2;
            const f32x2 dsq = d0 * d0 + d1 * d1 + d2 * d2;
            const f32x2 arg = dsq * B + (rx2 * A + syA);
            const f32x2 w = mk2(__builtin_amdgcn_exp2f(arg.x),
                                __builtin_amdgcn_exp2f(arg.y));
            wsum += w;
            a0 += w * v0;
            a1 += w * v1;
            a2 += w * v2;
        }
    }

    const int pid = ty * NP + tx;
    if (tz > 0) {
        s_comb[tz - 1][pid][0] = wsum;
        s_comb[tz - 1][pid][1] = a0;
        s_comb[tz - 1][pid][2] = a1;
        s_comb[tz - 1][pid][3] = a2;
    }
    __syncthreads();

    if (tz == 0) {
        #pragma unroll
        for (int t = 0; t < 2; ++t) {
            wsum += s_comb[t][pid][0];
            a0   += s_comb[t][pid][1];
            a1   += s_comb[t][pid][2];
            a2   += s_comb[t][pid][3];
        }
        const f32x2 inv = mk2(__builtin_amdgcn_rcpf(wsum.x),
                              __builtin_amdgcn_rcpf(wsum.y));   // wsum >= 1 (center w == 1)
        float* outb = out + (size_t)b * 3 * PLANE;
        const int oidx = oy * IMG_W + ox;
        const f32x2 o0 = a0 * inv, o1 = a1 * inv, o2 = a2 * inv;
        *reinterpret_cast<float2*>(&outb[oidx])             = make_float2(o0.x, o0.y);
        *reinterpret_cast<float2*>(&outb[PLANE + oidx])     = make_float2(o1.x, o1.y);
        *reinterpret_cast<float2*>(&outb[2 * PLANE + oidx]) = make_float2(o2.x, o2.y);
    }
}

extern "C" void kernel_launch(void* const* d_in, const int* in_sizes, int n_in,
                              void* d_out, int out_size, void* d_ws, size_t ws_size,
                              hipStream_t stream) {
    const float* input  = (const float*)d_in[0];
    const float* sigmas = (const float*)d_in[1];
    float* out = (float*)d_out;

    dim3 block(NP, TH, 3);                          // (8,8,3) = 192 threads, 3 waves
    dim3 grid(IMG_W / TW, IMG_H / TH, 2 * REPS);    // z: batch x replica (identical writes)
    abf_kernel<<<grid, block, 0, stream>>>(input, sigmas, out);
}

// Round 9
// 16.437 us; speedup vs baseline: 5.1470x; 5.1470x over previous
//
#include <hip/hip_runtime.h>
#include <hip/hip_bf16.h>

typedef float f32x2 __attribute__((ext_vector_type(2)));

#define IMG_H 384
#define IMG_W 384
#define KSZ 9
#define KR 4
#define TW 16                 // tile width (px) = 8 pixel-pairs
#define TH 8                  // tile height
#define NP (TW/2)             // 8 pairs per row
#define HW (TW + 2*KR)        // 24 halo width
#define HH (TH + 2*KR)        // 16 halo height
#define PST 37                // plane row stride (dwords); ODD -> window loads mix bank parity
                              // across rows (addr%32 = 5*ty + 2*tx + j) => ~2-way max (free)
#define PLANE (IMG_H * IMG_W)

static __device__ __forceinline__ f32x2 mk2(float a, float b) { f32x2 r; r.x = a; r.y = b; return r; }

__global__ __launch_bounds__(192) void abf_kernel(
    const float* __restrict__ input,   // [2][3][384][384]
    const float* __restrict__ sigmas,  // [2][2][384][384]
    float* __restrict__ out)           // [2][3][384][384]
{
    __shared__ float s_in[3 * HH * PST];          // ~7.1 KB, channel-planar
    __shared__ f32x2 s_comb[2][NP * TH][4];       // tz=1,2 partial sums, 4 KB

    const int b      = blockIdx.z;
    const int tile_x = blockIdx.x * TW;
    const int tile_y = blockIdx.y * TH;
    const int tx = threadIdx.x;  // 0..7  pair column
    const int ty = threadIdx.y;  // 0..7  row
    const int tz = threadIdx.z;  // 0..2  dy-group (wave-uniform)
    const int tid = (tz * TH + ty) * NP + tx;

    // ---- stage 24x16 halo, channel-planar; div/mod ONCE, loops are add-only ----
    {
        const int sy = tid / HW;          // 0..7   (one magic-mul sequence)
        const int sx = tid - sy * HW;     // 0..23
        const int gx = tile_x + sx - KR;
        const bool okx = (gx >= 0) & (gx < IMG_W);
        const float* inb = input + (size_t)b * 3 * PLANE;
        #pragma unroll
        for (int c = 0; c < 3; ++c) {
            #pragma unroll
            for (int k = 0; k < 2; ++k) {
                const int y  = sy + 8 * k;            // 0..15
                const int gy = tile_y + y - KR;
                float v = 0.f;
                if (okx & (gy >= 0) & (gy < IMG_H))
                    v = inb[c * PLANE + (gy << 8) + (gy << 7) + gx];  // gy*384 + gx
                s_in[(c * HH + y) * PST + sx] = v;
            }
        }
    }
    __syncthreads();

    const int lx = 2 * tx;           // tile-local col of pixel A (pixel B = lx+1)
    const int ox = tile_x + lx;
    const int oy = tile_y + ty;

    const float* sgb = sigmas + (size_t)b * 2 * PLANE;
    const int sidx = (oy << 8) + (oy << 7) + ox;
    const float sA0 = sgb[sidx],          sB0 = sgb[sidx + 1];
    const float sA1 = sgb[PLANE + sidx],  sB1 = sgb[PLANE + sidx + 1];
    const float isA = __builtin_amdgcn_rcpf(fabsf(sA0) + 1e-12f);
    const float isB = __builtin_amdgcn_rcpf(fabsf(sB0) + 1e-12f);
    const float irA = __builtin_amdgcn_rcpf(fabsf(sA1) + 1e-12f);
    const float irB = __builtin_amdgcn_rcpf(fabsf(sB1) + 1e-12f);
    // w = exp2(dsq*B + (rx2+ry2)*A), packed over the two pixels
    const f32x2 A = mk2(-0.72134752f * isA * isA, -0.72134752f * isB * isB);
    const f32x2 B = mk2(-0.72134752f * irA * irA, -0.72134752f * irB * irB);

    const int cb = (ty + KR) * PST + lx + KR;
    const f32x2 cen0 = mk2(s_in[0 * HH * PST + cb], s_in[0 * HH * PST + cb + 1]);
    const f32x2 cen1 = mk2(s_in[1 * HH * PST + cb], s_in[1 * HH * PST + cb + 1]);
    const f32x2 cen2 = mk2(s_in[2 * HH * PST + cb], s_in[2 * HH * PST + cb + 1]);

    f32x2 wsum = mk2(0.f, 0.f), a0 = wsum, a1 = wsum, a2 = wsum;

    // tz handles dy in {3tz, 3tz+1, 3tz+2} : perfect 3-way balance
    #pragma unroll 1
    for (int r = 0; r < 3; ++r) {
        const int dy = tz * 3 + r;
        const float ry2 = (float)((dy - KR) * (dy - KR));
        const f32x2 syA = ry2 * A;
        const int r0 = (0 * HH + ty + dy) * PST + lx;
        const int r1 = (1 * HH + ty + dy) * PST + lx;
        const int r2 = (2 * HH + ty + dy) * PST + lx;

        // register sliding window: 10 dwords per channel row, loaded once,
        // static indices only (adjacent pairs merge into ds_read2_b32)
        float w0[10], w1[10], w2[10];
        #pragma unroll
        for (int j = 0; j < 10; ++j) {
            w0[j] = s_in[r0 + j];
            w1[j] = s_in[r1 + j];
            w2[j] = s_in[r2 + j];
        }

        #pragma unroll
        for (int dx = 0; dx < KSZ; ++dx) {
            const float rx2 = (float)((dx - KR) * (dx - KR));
            const f32x2 v0 = mk2(w0[dx], w0[dx + 1]);
            const f32x2 v1 = mk2(w1[dx], w1[dx + 1]);
            const f32x2 v2 = mk2(w2[dx], w2[dx + 1]);
            const f32x2 d0 = v0 - cen0;
            const f32x2 d1 = v1 - cen1;
            const f32x2 d2 = v2 - cen2;
            const f32x2 dsq = d0 * d0 + d1 * d1 + d2 * d2;
            const f32x2 arg = dsq * B + (rx2 * A + syA);
            const f32x2 w = mk2(__builtin_amdgcn_exp2f(arg.x),
                                __builtin_amdgcn_exp2f(arg.y));
            wsum += w;
            a0 += w * v0;
            a1 += w * v1;
            a2 += w * v2;
        }
    }

    const int pid = ty * NP + tx;
    if (tz > 0) {
        s_comb[tz - 1][pid][0] = wsum;
        s_comb[tz - 1][pid][1] = a0;
        s_comb[tz - 1][pid][2] = a1;
        s_comb[tz - 1][pid][3] = a2;
    }
    __syncthreads();

    if (tz == 0) {
        #pragma unroll
        for (int t = 0; t < 2; ++t) {
            wsum += s_comb[t][pid][0];
            a0   += s_comb[t][pid][1];
            a1   += s_comb[t][pid][2];
            a2   += s_comb[t][pid][3];
        }
        const f32x2 inv = mk2(__builtin_amdgcn_rcpf(wsum.x),
                              __builtin_amdgcn_rcpf(wsum.y));   // wsum >= 1 (center w == 1)
        float* outb = out + (size_t)b * 3 * PLANE;
        const int oidx = (oy << 8) + (oy << 7) + ox;
        const f32x2 o0 = a0 * inv, o1 = a1 * inv, o2 = a2 * inv;
        *reinterpret_cast<float2*>(&outb[oidx])             = make_float2(o0.x, o0.y);
        *reinterpret_cast<float2*>(&outb[PLANE + oidx])     = make_float2(o1.x, o1.y);
        *reinterpret_cast<float2*>(&outb[2 * PLANE + oidx]) = make_float2(o2.x, o2.y);
    }
}

extern "C" void kernel_launch(void* const* d_in, const int* in_sizes, int n_in,
                              void* d_out, int out_size, void* d_ws, size_t ws_size,
                              hipStream_t stream) {
    const float* input  = (const float*)d_in[0];
    const float* sigmas = (const float*)d_in[1];
    float* out = (float*)d_out;

    dim3 block(NP, TH, 3);                          // (8,8,3) = 192 threads, 3 waves
    dim3 grid(IMG_W / TW, IMG_H / TH, 2);           // 24 x 48 x 2 = 2304 blocks (9/CU)
    abf_kernel<<<grid, block, 0, stream>>>(input, sigmas, out);
}

// Round 10
// 15.750 us; speedup vs baseline: 5.3716x; 1.0436x over previous
//
#include <hip/hip_runtime.h>
#include <hip/hip_bf16.h>

typedef float f32x2 __attribute__((ext_vector_type(2)));

#define IMG 384
#define KR 4
#define TW 16      // tile width (16 columns, 1 per thread-x)
#define TH 8       // tile height (each thread owns rows Y, Y+1 -> ty 0..3)
#define HW 24      // halo width
#define HH 16      // halo height
#define PRS 25     // pair-row stride in float2 units (odd -> 4-touch/bank floor, verified)
#define NE 8       // even-start row pairs: (0,1),(2,3),...,(14,15)
#define NO 7       // odd-start  row pairs: (1,2),(3,4),...,(13,14)
#define PLANE (IMG*IMG)

static __device__ __forceinline__ f32x2 mk2(float a, float b) { f32x2 r; r.x = a; r.y = b; return r; }

__global__ __launch_bounds__(192) void abf_kernel(
    const float* __restrict__ input,   // [2][3][384][384]
    const float* __restrict__ sigmas,  // [2][2][384][384]
    float* __restrict__ out)           // [2][3][384][384]
{
    __shared__ f32x2 sE[3 * NE * PRS];          // 4.8 KB: pairs starting at even halo rows
    __shared__ f32x2 sO[3 * NO * PRS];          // 4.2 KB: pairs starting at odd halo rows
    __shared__ f32x2 s_comb[2][TW * (TH/2)][4]; // 4 KB: tz=1,2 partial sums

    const int b      = blockIdx.z;
    const int tile_x = blockIdx.x * TW;
    const int tile_y = blockIdx.y * TH;
    const int tx = threadIdx.x;   // 0..15 column
    const int ty = threadIdx.y;   // 0..3  row-pair
    const int tz = threadIdx.z;   // 0..2  dy-group (wave-uniform)
    const int tid = tz * 64 + ty * TW + tx;

    // ---- stage 24x16 halo into BOTH parity copies (each value written <=2x) ----
    {
        const int sy = tid / HW;          // 0..7 (one magic-mul)
        const int sx = tid - sy * HW;     // 0..23
        const int gx = tile_x + sx - KR;
        const bool okx = (gx >= 0) & (gx < IMG);
        const float* inb = input + (size_t)b * 3 * PLANE;
        float* fE = (float*)sE;
        float* fO = (float*)sO;
        #pragma unroll
        for (int c = 0; c < 3; ++c) {
            #pragma unroll
            for (int k = 0; k < 2; ++k) {
                const int hy = sy + 8 * k;            // 0..15
                const int gy = tile_y + hy - KR;
                float v = 0.f;
                if (okx & (gy >= 0) & (gy < IMG))
                    v = inb[c * PLANE + (gy << 8) + (gy << 7) + gx];   // gy*384 + gx
                fE[((c * NE + (hy >> 1)) * PRS + sx) * 2 + (hy & 1)] = v;
                if (hy >= 1 && hy <= 14)
                    fO[((c * NO + ((hy - 1) >> 1)) * PRS + sx) * 2 + ((hy - 1) & 1)] = v;
            }
        }
    }
    __syncthreads();

    const int ox  = tile_x + tx;
    const int oyA = tile_y + 2 * ty;                 // pixel A row; pixel B = oyA+1
    const int siA = (oyA << 8) + (oyA << 7) + ox;    // oyA*384 + ox

    const float* sgb = sigmas + (size_t)b * 2 * PLANE;
    const float ssA = sgb[siA],         ssB = sgb[siA + IMG];
    const float srA = sgb[PLANE + siA], srB = sgb[PLANE + siA + IMG];
    const float isA = __builtin_amdgcn_rcpf(fabsf(ssA) + 1e-12f);
    const float isB = __builtin_amdgcn_rcpf(fabsf(ssB) + 1e-12f);
    const float irA = __builtin_amdgcn_rcpf(fabsf(srA) + 1e-12f);
    const float irB = __builtin_amdgcn_rcpf(fabsf(srB) + 1e-12f);
    // w = exp2(dsq*B + (rx2+ry2)*A), packed over the two (vertical) pixels
    const f32x2 A = mk2(-0.72134752f * isA * isA, -0.72134752f * isB * isB);
    const f32x2 B = mk2(-0.72134752f * irA * irA, -0.72134752f * irB * irB);

    // centers: halo rows (2ty+4, 2ty+5) = even-start pair (ty+2), col tx+4 -> aligned f32x2
    const f32x2 cen0 = sE[(0 * NE + ty + 2) * PRS + tx + 4];
    const f32x2 cen1 = sE[(1 * NE + ty + 2) * PRS + tx + 4];
    const f32x2 cen2 = sE[(2 * NE + ty + 2) * PRS + tx + 4];

    f32x2 wsum = mk2(0.f, 0.f), a0 = wsum, a1 = wsum, a2 = wsum;

    // tz handles dy in {3tz, 3tz+1, 3tz+2}; tap (dy,dx) = pair starting at halo row 2ty+dy
    #pragma unroll 1
    for (int r = 0; r < 3; ++r) {
        const int dy = tz * 3 + r;
        const float ry = (float)(dy - KR);
        const f32x2 syA = (ry * ry) * A;

        const f32x2 *p0, *p1, *p2;          // wave-uniform parity select
        if (dy & 1) {
            const int pr = ty + ((dy - 1) >> 1);
            p0 = &sO[(0 * NO + pr) * PRS + tx];
            p1 = &sO[(1 * NO + pr) * PRS + tx];
            p2 = &sO[(2 * NO + pr) * PRS + tx];
        } else {
            const int pr = ty + (dy >> 1);
            p0 = &sE[(0 * NE + pr) * PRS + tx];
            p1 = &sE[(1 * NE + pr) * PRS + tx];
            p2 = &sE[(2 * NE + pr) * PRS + tx];
        }

        // window: 9 aligned f32x2 per channel (ds_read_b64/b128-mergeable, conflict-free)
        f32x2 w0[9], w1[9], w2[9];
        #pragma unroll
        for (int j = 0; j < 9; ++j) { w0[j] = p0[j]; w1[j] = p1[j]; w2[j] = p2[j]; }

        #pragma unroll
        for (int dx = 0; dx < 9; ++dx) {
            const float rx2 = (float)((dx - KR) * (dx - KR));
            const f32x2 v0 = w0[dx], v1 = w1[dx], v2 = w2[dx];
            const f32x2 d0 = v0 - cen0;
            const f32x2 d1 = v1 - cen1;
            const f32x2 d2 = v2 - cen2;
            const f32x2 dsq = d0 * d0 + d1 * d1 + d2 * d2;   // pk mul + 2 pk fma
            const f32x2 arg = dsq * B + (rx2 * A + syA);     // pk fma chain
            const f32x2 w = mk2(__builtin_amdgcn_exp2f(arg.x),
                                __builtin_amdgcn_exp2f(arg.y));
            wsum += w;
            a0 += w * v0;
            a1 += w * v1;
            a2 += w * v2;
        }
    }

    const int pid = ty * TW + tx;   // 0..63
    if (tz > 0) {
        s_comb[tz - 1][pid][0] = wsum;
        s_comb[tz - 1][pid][1] = a0;
        s_comb[tz - 1][pid][2] = a1;
        s_comb[tz - 1][pid][3] = a2;
    }
    __syncthreads();

    if (tz == 0) {
        #pragma unroll
        for (int t = 0; t < 2; ++t) {
            wsum += s_comb[t][pid][0];
            a0   += s_comb[t][pid][1];
            a1   += s_comb[t][pid][2];
            a2   += s_comb[t][pid][3];
        }
        const f32x2 inv = mk2(__builtin_amdgcn_rcpf(wsum.x),
                              __builtin_amdgcn_rcpf(wsum.y));   // wsum >= 1 (center w == 1)
        float* outb = out + (size_t)b * 3 * PLANE;
        const f32x2 o0 = a0 * inv, o1 = a1 * inv, o2 = a2 * inv;
        outb[siA]                 = o0.x;  outb[siA + IMG]             = o0.y;
        outb[PLANE + siA]         = o1.x;  outb[PLANE + siA + IMG]     = o1.y;
        outb[2 * PLANE + siA]     = o2.x;  outb[2 * PLANE + siA + IMG] = o2.y;
    }
}

extern "C" void kernel_launch(void* const* d_in, const int* in_sizes, int n_in,
                              void* d_out, int out_size, void* d_ws, size_t ws_size,
                              hipStream_t stream) {
    const float* input  = (const float*)d_in[0];
    const float* sigmas = (const float*)d_in[1];
    float* out = (float*)d_out;

    dim3 block(TW, TH / 2, 3);                      // (16,4,3) = 192 threads, 3 waves
    dim3 grid(IMG / TW, IMG / TH, 2);               // 24 x 48 x 2 = 2304 blocks (9/CU)
    abf_kernel<<<grid, block, 0, stream>>>(input, sigmas, out);
}